// Round 2
// baseline (483.429 us; speedup 1.0000x reference)
//
#include <hip/hip_runtime.h>
#include <hip/hip_fp16.h>

typedef unsigned short u16;
using f32x4 = __attribute__((ext_vector_type(4))) float;
using half8 = __attribute__((ext_vector_type(8))) _Float16;

#define N_PTS 8192
#define D_DIM 768
#define TOPK  21
#define CAP   64        // candidate slots per row per stripe (E ~21, +9.5 sigma)
#define KSTEPS 12       // 768 / 64
#define NSTRIPE1 7      // stripes 1..7 handled by filter kernel

// ---------------- async global->LDS (16B per lane) ----------------
__device__ __forceinline__ void gload16(const void* g, void* l) {
    __builtin_amdgcn_global_load_lds(
        (const __attribute__((address_space(1))) void*)g,
        (__attribute__((address_space(3))) void*)l,
        16, 0, 0);
}

// ---------------- branch-free sorted top-k insert (ascending) ------
__device__ __forceinline__ void topk_insert(float (&t)[TOPK], float x) {
    if (x >= t[TOPK - 1]) return;
#pragma unroll
    for (int i = TOPK - 1; i >= 1; --i) {
        float tp = t[i - 1];
        t[i] = (x < tp) ? tp : fminf(x, t[i]);
    }
    t[0] = fminf(t[0], x);
}

// ---------------- kernel 1: fp32 -> fp16 + row norms + zero flags ----
__global__ __launch_bounds__(256) void prep_kernel(const float* __restrict__ X,
                                                   u16* __restrict__ Xh,
                                                   float* __restrict__ norms,
                                                   int* __restrict__ flags) {
    const int row = blockIdx.x;
    const int tid = threadIdx.x;
    const float* xr = X + (size_t)row * D_DIM;
    u16* hr = Xh + (size_t)row * D_DIM;
    float s = 0.f;
#pragma unroll
    for (int i = 0; i < 3; ++i) {
        float v = xr[tid + i * 256];
        _Float16 h = (_Float16)v;
        u16 hb;
        __builtin_memcpy(&hb, &h, 2);
        hr[tid + i * 256] = hb;
        float vb = (float)h;
        s += vb * vb;
    }
#pragma unroll
    for (int o = 32; o >= 1; o >>= 1) s += __shfl_down(s, o, 64);
    __shared__ float red[4];
    if ((tid & 63) == 0) red[tid >> 6] = s;
    __syncthreads();
    if (tid == 0) {
        norms[row] = red[0] + red[1] + red[2] + red[3];
        flags[row] = 0;
    }
}

// ---------------- kernel 2a: stripe-0 GEMM + exact per-(row,chunk) top-21 ----
// grid = 64 rowTiles * 8 colChunks (128 cols each) = 512 blocks.
__global__ __launch_bounds__(256) void gemm_tau_kernel(const u16* __restrict__ Xh,
                                                       const float* __restrict__ norms,
                                                       float* __restrict__ partials0) {
    __shared__ __align__(16) u16 As[128 * 64];
    __shared__ __align__(16) u16 Bs[128 * 64];
    __shared__ float Ss[128 * 65];
    __shared__ float nAs[128];
    __shared__ float nBs[128];

    const int tid  = threadIdx.x;
    const int lane = tid & 63;
    const int wid  = tid >> 6;
    const int wr   = wid >> 1;
    const int wc   = wid & 1;
    const int l16  = lane >> 4;
    const int l15  = lane & 15;

    const int bid     = blockIdx.x;
    const int rowTile = bid >> 3;
    const int chunk   = bid & 7;
    const int r0 = rowTile * 128;
    const int cb = chunk * 128;          // within stripe 0 (cols 0..1023)

    float t[TOPK];
#pragma unroll
    for (int i = 0; i < TOPK; ++i) t[i] = 3e38f;

    if (tid < 128) {
        nAs[tid] = norms[r0 + tid];
        nBs[tid] = norms[cb + tid];
    }

    const int rb   = tid >> 3;
    const int cole = (tid & 7) * 8;
    const int lofs = tid * 8;

    f32x4 acc[4][4];
#pragma unroll
    for (int m = 0; m < 4; ++m)
#pragma unroll
        for (int n = 0; n < 4; ++n) {
            f32x4 z = {0.f, 0.f, 0.f, 0.f};
            acc[m][n] = z;
        }

    for (int ks = 0; ks < KSTEPS; ++ks) {
        const int kofs = ks * 64;
#pragma unroll
        for (int i = 0; i < 4; ++i) {
            const int r = i * 32 + rb;
            gload16(Xh + (size_t)(r0 + r) * D_DIM + kofs + cole, &As[i * 2048 + lofs]);
            gload16(Xh + (size_t)(cb + r) * D_DIM + kofs + cole, &Bs[i * 2048 + lofs]);
        }
        __syncthreads();
#pragma unroll
        for (int kk = 0; kk < 2; ++kk) {
            const int ko = kk * 32 + l16 * 8;
            half8 af[4], bf[4];
#pragma unroll
            for (int m = 0; m < 4; ++m)
                af[m] = *reinterpret_cast<const half8*>(&As[(wr * 64 + m * 16 + l15) * 64 + ko]);
#pragma unroll
            for (int n = 0; n < 4; ++n)
                bf[n] = *reinterpret_cast<const half8*>(&Bs[(wc * 64 + n * 16 + l15) * 64 + ko]);
#pragma unroll
            for (int m = 0; m < 4; ++m)
#pragma unroll
                for (int n = 0; n < 4; ++n)
                    acc[m][n] = __builtin_amdgcn_mfma_f32_16x16x32_f16(af[m], bf[n], acc[m][n], 0, 0, 0);
        }
        __syncthreads();
    }

#pragma unroll
    for (int h = 0; h < 2; ++h) {
        if (wc == h) {
#pragma unroll
            for (int m = 0; m < 4; ++m)
#pragma unroll
                for (int n = 0; n < 4; ++n)
#pragma unroll
                    for (int r = 0; r < 4; ++r) {
                        const int ri = wr * 64 + m * 16 + l16 * 4 + r;
                        const int ci = n * 16 + l15;
                        Ss[ri * 65 + ci] = nAs[ri] + nBs[h * 64 + ci] - 2.0f * acc[m][n][r];
                    }
        }
        __syncthreads();
        {
            const int srow = tid >> 1;
            const int sc0  = (tid & 1) * 32;
            const float* sr = &Ss[srow * 65 + sc0];
            for (int j = 0; j < 32; ++j) topk_insert(t, sr[j]);
        }
        __syncthreads();
    }

    // merge lane pairs; even lane holds top-21 of its row over this 128-col chunk
#pragma unroll
    for (int i = 0; i < TOPK; ++i) {
        float pv = __shfl_xor(t[i], 1, 64);
        if ((tid & 1) == 0) topk_insert(t, pv);
    }
    if ((tid & 1) == 0) {
        const int row = r0 + (tid >> 1);
        // transposed layout: [(chunk*21 + i) * 8192 + row]
#pragma unroll
        for (int i = 0; i < TOPK; ++i)
            partials0[((size_t)(chunk * TOPK + i)) * N_PTS + row] = t[i];
    }
}

// ---------------- kernel 2b: merge 8 chunk-partials -> stripe-0 top-21 ----
__global__ __launch_bounds__(256) void tau_merge_kernel(const float* __restrict__ partials0,
                                                        float* __restrict__ s0top) {
    const int row = blockIdx.x * 256 + threadIdx.x;
    float t[TOPK];
#pragma unroll
    for (int i = 0; i < TOPK; ++i) t[i] = 3e38f;
    for (int c = 0; c < 8; ++c)
#pragma unroll
        for (int i = 0; i < TOPK; ++i)
            topk_insert(t, partials0[((size_t)(c * TOPK + i)) * N_PTS + row]);
#pragma unroll
    for (int i = 0; i < TOPK; ++i)
        s0top[(size_t)i * N_PTS + row] = t[i];   // ascending; [20] is tau
}

// ---------------- kernel 3: stripes 1..7 GEMM + threshold filter ----
// grid = 64 rowTiles * 7 stripes = 448 blocks.
__global__ __launch_bounds__(256) void gemm_filter_kernel(const u16* __restrict__ Xh,
                                                          const float* __restrict__ norms,
                                                          const float* __restrict__ s0top,
                                                          float* __restrict__ cand_g,
                                                          int* __restrict__ cnt_g,
                                                          int* __restrict__ flags) {
    __shared__ __align__(16) u16 As[128 * 64];
    __shared__ __align__(16) u16 Bs[128 * 64];
    __shared__ float cand[128][CAP];
    __shared__ int   cnt[128];
    __shared__ float nAs[128];
    __shared__ float nBsArr[128];
    __shared__ float thrH[128];          // 0.5*(nA - (tau+1))

    const int tid  = threadIdx.x;
    const int lane = tid & 63;
    const int wid  = tid >> 6;
    const int wr   = wid >> 1;
    const int wc   = wid & 1;
    const int l16  = lane >> 4;
    const int l15  = lane & 15;

    const int bid     = blockIdx.x;
    const int stripe  = bid % 7;         // 0..6 -> global stripe 1..7
    const int rowTile = bid / 7;
    const int r0 = rowTile * 128;
    const int c0 = (stripe + 1) * 1024;

    if (tid < 128) {
        const float na = norms[r0 + tid];
        nAs[tid]  = na;
        thrH[tid] = 0.5f * (na - (s0top[(size_t)(TOPK - 1) * N_PTS + r0 + tid] + 1.0f));
        cnt[tid]  = 0;
    }
    __syncthreads();

    // hoist per-lane row-wise constants
    float thrMR[4][4], nAmr[4][4];
#pragma unroll
    for (int m = 0; m < 4; ++m)
#pragma unroll
        for (int r = 0; r < 4; ++r) {
            const int ri = wr * 64 + m * 16 + l16 * 4 + r;
            thrMR[m][r] = thrH[ri];
            nAmr[m][r]  = nAs[ri];
        }

    const int rb   = tid >> 3;
    const int cole = (tid & 7) * 8;
    const int lofs = tid * 8;

    for (int ct = 0; ct < 8; ++ct) {
        const int cb = c0 + ct * 128;
        __syncthreads();                 // guard nBsArr overwrite
        if (tid < 128) nBsArr[tid] = norms[cb + tid];

        f32x4 acc[4][4];
#pragma unroll
        for (int m = 0; m < 4; ++m)
#pragma unroll
            for (int n = 0; n < 4; ++n) {
                f32x4 z = {0.f, 0.f, 0.f, 0.f};
                acc[m][n] = z;
            }

        for (int ks = 0; ks < KSTEPS; ++ks) {
            const int kofs = ks * 64;
#pragma unroll
            for (int i = 0; i < 4; ++i) {
                const int r = i * 32 + rb;
                gload16(Xh + (size_t)(r0 + r) * D_DIM + kofs + cole, &As[i * 2048 + lofs]);
                gload16(Xh + (size_t)(cb + r) * D_DIM + kofs + cole, &Bs[i * 2048 + lofs]);
            }
            __syncthreads();
#pragma unroll
            for (int kk = 0; kk < 2; ++kk) {
                const int ko = kk * 32 + l16 * 8;
                half8 af[4], bf[4];
#pragma unroll
                for (int m = 0; m < 4; ++m)
                    af[m] = *reinterpret_cast<const half8*>(&As[(wr * 64 + m * 16 + l15) * 64 + ko]);
#pragma unroll
                for (int n = 0; n < 4; ++n)
                    bf[n] = *reinterpret_cast<const half8*>(&Bs[(wc * 64 + n * 16 + l15) * 64 + ko]);
#pragma unroll
                for (int m = 0; m < 4; ++m)
#pragma unroll
                    for (int n = 0; n < 4; ++n)
                        acc[m][n] = __builtin_amdgcn_mfma_f32_16x16x32_f16(af[m], bf[n], acc[m][n], 0, 0, 0);
            }
            __syncthreads();
        }

        // filter epilogue on registers: r2 < tau+1  <=>  dot > thrH(row) + 0.5*nB(col)
        float nBc[4], hb[4];
#pragma unroll
        for (int n = 0; n < 4; ++n) {
            const int ci = wc * 64 + n * 16 + l15;
            nBc[n] = nBsArr[ci];
            hb[n]  = 0.5f * nBc[n];
        }
#pragma unroll
        for (int m = 0; m < 4; ++m)
#pragma unroll
            for (int n = 0; n < 4; ++n)
#pragma unroll
                for (int r = 0; r < 4; ++r) {
                    const float d = acc[m][n][r];
                    if (d > thrMR[m][r] + hb[n]) {
                        const int ri = wr * 64 + m * 16 + l16 * 4 + r;
                        const float val = nAmr[m][r] + nBc[n] - 2.0f * d;
                        const int idx = atomicAdd(&cnt[ri], 1);
                        if (idx < CAP) cand[ri][idx] = val;
                    }
                }
    }

    __syncthreads();
    if (tid < 128) {
        const int row = r0 + tid;
        const int c = cnt[tid];
        const int cw = (c < CAP) ? c : CAP;
        cnt_g[(size_t)stripe * N_PTS + row] = cw;
        for (int j = 0; j < cw; ++j)
            cand_g[((size_t)(stripe * CAP + j)) * N_PTS + row] = cand[tid][j];
        if (c > CAP) flags[row] = 1;
    }
}

// ---------------- kernel 4: merge candidates + LID math ----------------
__global__ __launch_bounds__(256) void finalize_kernel(const float* __restrict__ cand_g,
                                                       const int* __restrict__ cnt_g,
                                                       const float* __restrict__ s0top,
                                                       const int* __restrict__ flags,
                                                       const u16* __restrict__ Xh,
                                                       const float* __restrict__ norms,
                                                       float* __restrict__ out) {
    const int row = blockIdx.x * 256 + threadIdx.x;
    if (row >= N_PTS) return;

    float t[TOPK];
#pragma unroll
    for (int i = 0; i < TOPK; ++i)
        t[i] = s0top[(size_t)i * N_PTS + row];   // exact stripe-0 top-21, ascending

    for (int s = 0; s < NSTRIPE1; ++s) {
        const int c = cnt_g[(size_t)s * N_PTS + row];
        for (int j = 0; j < c; ++j)
            topk_insert(t, cand_g[((size_t)(s * CAP + j)) * N_PTS + row]);
    }

    if (flags[row]) {   // overflow fallback (expected never): exact brute force
#pragma unroll
        for (int i = 0; i < TOPK; ++i) t[i] = 3e38f;
        const u16* xr = Xh + (size_t)row * D_DIM;
        const float nr = norms[row];
        for (int col = 0; col < N_PTS; ++col) {
            const u16* xc = Xh + (size_t)col * D_DIM;
            float dot = 0.f;
            for (int d = 0; d < D_DIM; ++d) {
                _Float16 a, b;
                __builtin_memcpy(&a, &xr[d], 2);
                __builtin_memcpy(&b, &xc[d], 2);
                dot += (float)a * (float)b;
            }
            topk_insert(t, nr + norms[col] - 2.f * dot);
        }
    }

    float S = 0.f, amin = 3e38f, amax = -3e38f;
#pragma unroll
    for (int i = 0; i < TOPK; ++i) {
        float a = sqrtf(fmaxf(t[i], 1e-12f));
        S += a;
        amin = fminf(amin, a);
        amax = fmaxf(amax, a);
    }
    float m = (S - amin - amax) * (1.0f / 19.0f);
    float lid = m / (amax - m);
    out[row] = -fabsf(logf(lid));
}

extern "C" void kernel_launch(void* const* d_in, const int* in_sizes, int n_in,
                              void* d_out, int out_size, void* d_ws, size_t ws_size,
                              hipStream_t stream) {
    const float* X = (const float*)d_in[0];
    float* out = (float*)d_out;
    char* ws = (char*)d_ws;

    u16*   Xh        = (u16*)ws;                       // 12,582,912 B
    float* norms     = (float*)(ws + 12582912);        //     32,768 B
    float* partials0 = (float*)(ws + 12615680);        //  5,505,024 B (8*21*8192*4)
    float* s0top     = (float*)(ws + 18120704);        //    688,128 B (21*8192*4)
    float* cand_g    = (float*)(ws + 18808832);        // 14,680,064 B (7*64*8192*4)
    int*   cnt_g     = (int*)(ws + 33488896);          //    229,376 B
    int*   flags     = (int*)(ws + 33718272);          //     32,768 B

    prep_kernel<<<N_PTS, 256, 0, stream>>>(X, Xh, norms, flags);
    gemm_tau_kernel<<<512, 256, 0, stream>>>(Xh, norms, partials0);
    tau_merge_kernel<<<N_PTS / 256, 256, 0, stream>>>(partials0, s0top);
    gemm_filter_kernel<<<64 * NSTRIPE1, 256, 0, stream>>>(Xh, norms, s0top, cand_g, cnt_g, flags);
    finalize_kernel<<<N_PTS / 256, 256, 0, stream>>>(cand_g, cnt_g, s0top, flags, Xh, norms, out);
}

// Round 3
// 212.278 us; speedup vs baseline: 2.2773x; 2.2773x over previous
//
#include <hip/hip_runtime.h>
#include <hip/hip_fp16.h>
#include <string.h>

typedef unsigned short u16;
using f32x4 = __attribute__((ext_vector_type(4))) float;
using half8 = __attribute__((ext_vector_type(8))) _Float16;
using us8   = __attribute__((ext_vector_type(8))) unsigned short;

#define N_PTS 8192
#define D_DIM 768
#define TOPK  21
#define KSTEPS 12        // 768 / 64
#define CAPL  12         // LDS candidate slots per row per block (E=2.6, P(>12)~2e-6 -> global spill)
#define CAPG  320        // global candidate slots per row (E=168, overflow prob ~1e-26)

// ---------------- async global->LDS (16B per lane) ----------------
__device__ __forceinline__ void gload16(const void* g, void* l) {
    __builtin_amdgcn_global_load_lds(
        (const __attribute__((address_space(1))) void*)g,
        (__attribute__((address_space(3))) void*)l,
        16, 0, 0);
}

// ---------------- wave (64-lane) reductions ----------------
__device__ __forceinline__ int wred_sum_i(int c) {
#pragma unroll
    for (int o = 32; o >= 1; o >>= 1) c += __shfl_xor(c, o, 64);
    return c;
}
__device__ __forceinline__ float wred_sum_f(float c) {
#pragma unroll
    for (int o = 32; o >= 1; o >>= 1) c += __shfl_xor(c, o, 64);
    return c;
}
__device__ __forceinline__ float wred_min_f(float c) {
#pragma unroll
    for (int o = 32; o >= 1; o >>= 1) c = fminf(c, __shfl_xor(c, o, 64));
    return c;
}

// ---------------- kernel 1: fp32 -> fp16 + row norms + zero counters ----
__global__ __launch_bounds__(256) void prep_kernel(const float* __restrict__ X,
                                                   u16* __restrict__ Xh,
                                                   float* __restrict__ norms,
                                                   int* __restrict__ cnt_g) {
    const int row = blockIdx.x;
    const int tid = threadIdx.x;
    const float* xr = X + (size_t)row * D_DIM;
    u16* hr = Xh + (size_t)row * D_DIM;
    float s = 0.f;
#pragma unroll
    for (int i = 0; i < 3; ++i) {
        float v = xr[tid + i * 256];
        _Float16 h = (_Float16)v;
        u16 hb;
        __builtin_memcpy(&hb, &h, 2);
        hr[tid + i * 256] = hb;
        float vb = (float)h;
        s += vb * vb;
    }
#pragma unroll
    for (int o = 32; o >= 1; o >>= 1) s += __shfl_down(s, o, 64);
    __shared__ float red[4];
    if ((tid & 63) == 0) red[tid >> 6] = s;
    __syncthreads();
    if (tid == 0) {
        norms[row] = red[0] + red[1] + red[2] + red[3];
        cnt_g[row] = 0;
    }
}

// ---------------- kernel 2: sample GEMM (cols 0..1023) -> d2 as fp16 ----
// grid = 64 rowTiles * 8 chunks = 512 blocks.
__global__ __launch_bounds__(256, 4) void gemm_tau_kernel(const u16* __restrict__ Xh,
                                                          const float* __restrict__ norms,
                                                          u16* __restrict__ d2h) {
    __shared__ __align__(16) u16 As[128 * 64];
    __shared__ __align__(16) u16 Bs[128 * 64];
    __shared__ float nAs[128];
    __shared__ float nBs[128];

    const int tid  = threadIdx.x;
    const int lane = tid & 63;
    const int wid  = tid >> 6;
    const int wr   = wid >> 1;
    const int wc   = wid & 1;
    const int l16  = lane >> 4;
    const int l15  = lane & 15;

    const int bid = blockIdx.x;
    const int swz = (bid & 7) * 64 + (bid >> 3);   // XCD-contiguous
    const int rowTile = swz >> 3;
    const int chunk   = swz & 7;
    const int r0 = rowTile * 128;
    const int cb = chunk * 128;

    if (tid < 128) {
        nAs[tid] = norms[r0 + tid];
        nBs[tid] = norms[cb + tid];
    }

    const int rb   = tid >> 3;
    const int cole = (tid & 7) * 8;
    const int lofs = tid * 8;

    f32x4 acc[4][4];
#pragma unroll
    for (int m = 0; m < 4; ++m)
#pragma unroll
        for (int n = 0; n < 4; ++n) {
            f32x4 z = {0.f, 0.f, 0.f, 0.f};
            acc[m][n] = z;
        }

    for (int ks = 0; ks < KSTEPS; ++ks) {
        const int kofs = ks * 64;
#pragma unroll
        for (int i = 0; i < 4; ++i) {
            const int r = i * 32 + rb;
            gload16(Xh + (size_t)(r0 + r) * D_DIM + kofs + cole, &As[i * 2048 + lofs]);
            gload16(Xh + (size_t)(cb + r) * D_DIM + kofs + cole, &Bs[i * 2048 + lofs]);
        }
        __syncthreads();
#pragma unroll
        for (int kk = 0; kk < 2; ++kk) {
            const int ko = kk * 32 + l16 * 8;
            half8 af[4], bf[4];
#pragma unroll
            for (int m = 0; m < 4; ++m)
                af[m] = *reinterpret_cast<const half8*>(&As[(wr * 64 + m * 16 + l15) * 64 + ko]);
#pragma unroll
            for (int n = 0; n < 4; ++n)
                bf[n] = *reinterpret_cast<const half8*>(&Bs[(wc * 64 + n * 16 + l15) * 64 + ko]);
#pragma unroll
            for (int m = 0; m < 4; ++m)
#pragma unroll
                for (int n = 0; n < 4; ++n)
                    acc[m][n] = __builtin_amdgcn_mfma_f32_16x16x32_f16(af[m], bf[n], acc[m][n], 0, 0, 0);
        }
        __syncthreads();
    }

    // epilogue: d2 = nA + nB - 2*dot, clamp >= 0, store fp16
    float nAr[4][4], nBc[4];
#pragma unroll
    for (int m = 0; m < 4; ++m)
#pragma unroll
        for (int r = 0; r < 4; ++r) nAr[m][r] = nAs[wr * 64 + m * 16 + l16 * 4 + r];
#pragma unroll
    for (int n = 0; n < 4; ++n) nBc[n] = nBs[wc * 64 + n * 16 + l15];

#pragma unroll
    for (int m = 0; m < 4; ++m)
#pragma unroll
        for (int n = 0; n < 4; ++n)
#pragma unroll
            for (int r = 0; r < 4; ++r) {
                const int ri = r0 + wr * 64 + m * 16 + l16 * 4 + r;
                const int ci = cb + wc * 64 + n * 16 + l15;
                float d2 = fmaxf(nAr[m][r] + nBc[n] - 2.0f * acc[m][n][r], 0.0f);
                _Float16 h = (_Float16)d2;
                u16 hb;
                __builtin_memcpy(&hb, &h, 2);
                d2h[(size_t)ri * 1024 + ci] = hb;
            }
}

// ---------------- kernel 3: per-row 21st-smallest of sample via bit search ----
// one wave per row; grid = 8192/4 = 2048 blocks of 256.
__global__ __launch_bounds__(256) void tau_select_kernel(const u16* __restrict__ d2h,
                                                         float* __restrict__ tauB) {
    const int tid  = threadIdx.x;
    const int lane = tid & 63;
    const int row  = blockIdx.x * 4 + (tid >> 6);

    const us8* p = (const us8*)(d2h + (size_t)row * 1024);
    us8 v0 = p[lane * 2];
    us8 v1 = p[lane * 2 + 1];

    unsigned lo = 0, hi = 0x7BFF;   // max finite fp16
#pragma unroll
    for (int it = 0; it < 15; ++it) {
        const unsigned mid = (lo + hi) >> 1;
        int c = 0;
#pragma unroll
        for (int j = 0; j < 8; ++j) c += ((unsigned)v0[j] <= mid) + ((unsigned)v1[j] <= mid);
        c = wred_sum_i(c);
        if (c >= TOPK) hi = mid; else lo = mid + 1;
    }
    if (lane == 0) {
        u16 b = (u16)lo;
        _Float16 h;
        __builtin_memcpy(&h, &b, 2);
        tauB[row] = (float)h + 2.0f;   // upper bound on true 21st d2, +slack
    }
}

// ---------------- kernel 4: full-matrix GEMM + threshold filter ----
// grid = 64 * 64 = 4096 blocks, each one 128x128 output tile.
__global__ __launch_bounds__(256, 4) void gemm_filter_kernel(const u16* __restrict__ Xh,
                                                             const float* __restrict__ norms,
                                                             const float* __restrict__ tauB,
                                                             float* __restrict__ cand_g,
                                                             int* __restrict__ cnt_g) {
    __shared__ __align__(16) u16 As[128 * 64];
    __shared__ __align__(16) u16 Bs[128 * 64];
    __shared__ float candL[128][CAPL];
    __shared__ int   cntL[128];
    __shared__ float nAs[128];
    __shared__ float nBs[128];
    __shared__ float thrA[128];      // 0.5*(nA - tauP)

    const int tid  = threadIdx.x;
    const int lane = tid & 63;
    const int wid  = tid >> 6;
    const int wr   = wid >> 1;
    const int wc   = wid & 1;
    const int l16  = lane >> 4;
    const int l15  = lane & 15;

    const int bid = blockIdx.x;
    const int swz = (bid & 7) * 512 + (bid >> 3);  // XCD-contiguous: 8 rowTiles/XCD
    const int rowTile = swz >> 6;
    const int colTile = swz & 63;
    const int r0 = rowTile * 128;
    const int c0 = colTile * 128;

    if (tid < 128) {
        const float na = norms[r0 + tid];
        nAs[tid]  = na;
        thrA[tid] = 0.5f * (na - tauB[r0 + tid]);
        nBs[tid]  = norms[c0 + tid];
        cntL[tid] = 0;
    }

    const int rb   = tid >> 3;
    const int cole = (tid & 7) * 8;
    const int lofs = tid * 8;

    f32x4 acc[4][4];
#pragma unroll
    for (int m = 0; m < 4; ++m)
#pragma unroll
        for (int n = 0; n < 4; ++n) {
            f32x4 z = {0.f, 0.f, 0.f, 0.f};
            acc[m][n] = z;
        }

    for (int ks = 0; ks < KSTEPS; ++ks) {
        const int kofs = ks * 64;
#pragma unroll
        for (int i = 0; i < 4; ++i) {
            const int r = i * 32 + rb;
            gload16(Xh + (size_t)(r0 + r) * D_DIM + kofs + cole, &As[i * 2048 + lofs]);
            gload16(Xh + (size_t)(c0 + r) * D_DIM + kofs + cole, &Bs[i * 2048 + lofs]);
        }
        __syncthreads();
#pragma unroll
        for (int kk = 0; kk < 2; ++kk) {
            const int ko = kk * 32 + l16 * 8;
            half8 af[4], bf[4];
#pragma unroll
            for (int m = 0; m < 4; ++m)
                af[m] = *reinterpret_cast<const half8*>(&As[(wr * 64 + m * 16 + l15) * 64 + ko]);
#pragma unroll
            for (int n = 0; n < 4; ++n)
                bf[n] = *reinterpret_cast<const half8*>(&Bs[(wc * 64 + n * 16 + l15) * 64 + ko]);
#pragma unroll
            for (int m = 0; m < 4; ++m)
#pragma unroll
                for (int n = 0; n < 4; ++n)
                    acc[m][n] = __builtin_amdgcn_mfma_f32_16x16x32_f16(af[m], bf[n], acc[m][n], 0, 0, 0);
        }
        __syncthreads();
    }

    // filter epilogue: d2 < tauP  <=>  dot > 0.5*(nA - tauP) + 0.5*nB
    float thrM[4][4], nAr[4][4], nBc[4], hb[4];
#pragma unroll
    for (int m = 0; m < 4; ++m)
#pragma unroll
        for (int r = 0; r < 4; ++r) {
            const int ri = wr * 64 + m * 16 + l16 * 4 + r;
            thrM[m][r] = thrA[ri];
            nAr[m][r]  = nAs[ri];
        }
#pragma unroll
    for (int n = 0; n < 4; ++n) {
        const int ci = wc * 64 + n * 16 + l15;
        nBc[n] = nBs[ci];
        hb[n]  = 0.5f * nBc[n];
    }

#pragma unroll
    for (int m = 0; m < 4; ++m)
#pragma unroll
        for (int n = 0; n < 4; ++n)
#pragma unroll
            for (int r = 0; r < 4; ++r) {
                const float d = acc[m][n][r];
                if (d > thrM[m][r] + hb[n]) {
                    const int ri = wr * 64 + m * 16 + l16 * 4 + r;
                    const float val = nAr[m][r] + nBc[n] - 2.0f * d;
                    const int idx = atomicAdd(&cntL[ri], 1);
                    if (idx < CAPL) {
                        candL[ri][idx] = val;
                    } else {                       // rare LDS overflow: spill direct
                        const int g = atomicAdd(&cnt_g[r0 + ri], 1);
                        if (g < CAPG) cand_g[(size_t)(r0 + ri) * CAPG + g] = val;
                    }
                }
            }

    __syncthreads();
    if (tid < 128) {
        const int row = r0 + tid;
        const int c = (cntL[tid] < CAPL) ? cntL[tid] : CAPL;
        if (c > 0) {
            const int base = atomicAdd(&cnt_g[row], c);
            for (int j = 0; j < c; ++j) {
                const int s = base + j;
                if (s < CAPG) cand_g[(size_t)row * CAPG + s] = candL[tid][j];
            }
        }
    }
}

// ---------------- kernel 5: per-row top-21 stats from candidates + LID ----
// one wave per row; grid = 2048 blocks of 256.
__global__ __launch_bounds__(256) void finalize_kernel(const float* __restrict__ cand_g,
                                                       const int* __restrict__ cnt_g,
                                                       float* __restrict__ out) {
    const int tid  = threadIdx.x;
    const int lane = tid & 63;
    const int row  = blockIdx.x * 4 + (tid >> 6);

    int cnt = cnt_g[row];
    if (cnt > CAPG) cnt = CAPG;
    const float INFV = __uint_as_float(0x7F800000u);

    float v[5];
    unsigned b[5];
#pragma unroll
    for (int j = 0; j < 5; ++j) {
        const int s = lane + 64 * j;
        v[j] = (s < cnt) ? fmaxf(cand_g[(size_t)row * CAPG + s], 0.0f) : INFV;
        b[j] = __float_as_uint(v[j]);
    }

    // binary search on float bits for the 21st-smallest d2
    unsigned lo = 0, hi = 0x7F7FFFFFu;
#pragma unroll
    for (int it = 0; it < 31; ++it) {
        const unsigned mid = (lo + hi) >> 1;
        int c = 0;
#pragma unroll
        for (int j = 0; j < 5; ++j) c += (b[j] <= mid);
        c = wred_sum_i(c);
        if (c >= TOPK) hi = mid; else lo = mid + 1;
    }
    const float th = __uint_as_float(lo);   // a20^2

    int clt = 0;
    float slt = 0.f, mn = INFV;
#pragma unroll
    for (int j = 0; j < 5; ++j) {
        if (b[j] < lo) {
            clt += 1;
            slt += sqrtf(fmaxf(v[j], 1e-12f));
        }
        mn = fminf(mn, v[j]);
    }
    clt = wred_sum_i(clt);
    slt = wred_sum_f(slt);
    mn  = wred_min_f(mn);

    if (lane == 0) {
        const float a20 = sqrtf(fmaxf(th, 1e-12f));
        const float a0  = sqrtf(fmaxf(mn, 1e-12f));
        const float S21 = slt + (float)(TOPK - clt) * a20;
        const float m   = (S21 - a0 - a20) * (1.0f / 19.0f);
        const float lid = m / (a20 - m);
        out[row] = -fabsf(logf(lid));
    }
}

extern "C" void kernel_launch(void* const* d_in, const int* in_sizes, int n_in,
                              void* d_out, int out_size, void* d_ws, size_t ws_size,
                              hipStream_t stream) {
    const float* X = (const float*)d_in[0];
    float* out = (float*)d_out;
    char* ws = (char*)d_ws;

    u16*   Xh    = (u16*)ws;                      // 12,582,912 B
    float* norms = (float*)(ws + 12582912);       //     32,768 B
    float* tauB  = (float*)(ws + 12615680);       //     32,768 B
    int*   cnt_g = (int*)(ws + 12648448);         //     32,768 B
    u16*   d2h   = (u16*)(ws + 12681216);         // 16,777,216 B (8192x1024 fp16)
    // cand_g aliases d2h: filter runs strictly after tau_select consumed d2h
    float* cand_g = (float*)(ws + 12681216);      // 10,485,760 B (8192x320 f32)

    prep_kernel<<<N_PTS, 256, 0, stream>>>(X, Xh, norms, cnt_g);
    gemm_tau_kernel<<<512, 256, 0, stream>>>(Xh, norms, d2h);
    tau_select_kernel<<<N_PTS / 4, 256, 0, stream>>>(d2h, tauB);
    gemm_filter_kernel<<<4096, 256, 0, stream>>>(Xh, norms, tauB, cand_g, cnt_g);
    finalize_kernel<<<N_PTS / 4, 256, 0, stream>>>(cand_g, cnt_g, out);
}